// Round 14
// baseline (167.354 us; speedup 1.0000x reference)
//
#include <hip/hip_runtime.h>

#define NPI 50      // nodes per inner graph
#define EPI 400     // edges per inner graph
#define NPO 125     // nodes per outer graph
#define EPO 1000    // edges per outer graph
#define N_IN 100000
#define N_OUT 2000
#define NB 16       // batch graphs
#define NC 10
#define OB 128      // outer kernel blocks

typedef _Float16 half_t;
typedef _Float16 f16x8 __attribute__((ext_vector_type(8)));
typedef float f32x4 __attribute__((ext_vector_type(4)));

#define MFMA(a, b, c) __builtin_amdgcn_mfma_f32_16x16x32_f16(a, b, c, 0, 0, 0)

__device__ __forceinline__ void lds_barrier() {
    asm volatile("s_waitcnt lgkmcnt(0)" ::: "memory");
    __builtin_amdgcn_s_barrier();
}

// Swizzled LDS helpers. XOR of (row&7) into byte bits 4..6 keeps ds_read_b128
// conflict-free when 16 lanes read 16 consecutive rows.
__device__ __forceinline__ f16x8 lds_ld8(const half_t* base, int row, int k, int strideB) {
    return *(const f16x8*)((const char*)base + row * strideB + ((k * 2) ^ ((row & 7) << 4)));
}
__device__ __forceinline__ void lds_st1(half_t* base, int row, int col, int strideB, float v) {
    *(half_t*)((char*)base + row * strideB + ((col * 2) ^ ((row & 7) << 4))) = (half_t)v;
}
__device__ __forceinline__ void lds_st1h(half_t* base, int row, int col, int strideB, half_t v) {
    *(half_t*)((char*)base + row * strideB + ((col * 2) ^ ((row & 7) << 4))) = v;
}
// per-wave/block scratch, stride-parameterized, XOR (row&3)<<4
__device__ __forceinline__ f16x8 scrS_ld8(const half_t* base, int row, int k, int strideB) {
    return *(const f16x8*)((const char*)base + row * strideB + ((k * 2) ^ ((row & 3) << 4)));
}
__device__ __forceinline__ void scrS_st1(half_t* base, int row, int col, int strideB, float v) {
    *(half_t*)((char*)base + row * strideB + ((col * 2) ^ ((row & 3) << 4))) = (half_t)v;
}

// ---------------------------------------------------------------------------
// k_preW12: convert W1,W2 -> WT1,WT2 (f16, transposed) AND zero the sync
// counters + global Af scratch used by k_outer_one (replay-safe reset).
// ---------------------------------------------------------------------------
__global__ __launch_bounds__(256) void k_preW12(
    const float* __restrict__ W1, const float* __restrict__ W2,
    half_t* __restrict__ WT1, half_t* __restrict__ WT2,
    int* __restrict__ zbase, int zcount)
{
    int i = blockIdx.x * 256 + threadIdx.x;
    if (i < 8192) {
        int c = i & 127, k = i >> 7;
        WT1[c * 64 + k] = (half_t)W1[k * 128 + c];
    } else {
        int ii = i - 8192;
        int c = ii & 127, k = ii >> 7;
        WT2[c * 128 + k] = (half_t)W2[k * 128 + c];
    }
    for (int j = i; j < zcount; j += 96 * 256) zbase[j] = 0;
}

// ---------------------------------------------------------------------------
// Inner fused (r12/r13-proven, feat-major mergedT tail).
// ---------------------------------------------------------------------------
__global__ __launch_bounds__(256, 5) void k_inner(
    const float* __restrict__ X, const float* __restrict__ outfeat,
    const float* __restrict__ ew, const int* __restrict__ esrc,
    const int* __restrict__ edst,
    const half_t* __restrict__ WT1, const float* __restrict__ b1,
    const half_t* __restrict__ WT2, const float* __restrict__ b2,
    half_t* __restrict__ mergedT)
{
    __shared__ alignas(16) char smem[21504];
    half_t* R2  = (half_t*)smem;
    float*  Af  = (float*)smem;
    half_t* scr = (half_t*)(smem + 16384);
    float*  pool= (float*)(smem + 20480);
    int*    cO  = (int*)(smem + 20992);
    int*    cI  = (int*)(smem + 21248);

    const int g = blockIdx.x, t = threadIdx.x;
    const int w = t >> 6, l = t & 63, lr = l & 15, lk = l >> 4;
    const int nb = g * NPI, eb = g * EPI;
    half_t* scrw = scr + w * 512;

    float ofv = (t < 64) ? outfeat[(size_t)g * 64 + t] : 0.f;
    int s0e, d0e; float w0e;
    { int e = eb + t; s0e = esrc[e] - nb; d0e = edst[e] - nb; w0e = ew[e]; }
    int s1e = 0, d1e = 0; float w1e = 0.f;
    const bool e1v = (t + 256 < EPI);
    if (e1v) { int e = eb + t + 256; s1e = esrc[e] - nb; d1e = edst[e] - nb; w1e = ew[e]; }
    const int srow = t >> 2, qc = t & 3;
    f16x8 xh0 = {}, xh1 = {};
    if (srow < NPI) {
        const float* xp = &X[(size_t)(nb + srow) * 64 + qc * 16];
        float4 a = *(const float4*)(xp + 0), b = *(const float4*)(xp + 4);
        float4 c = *(const float4*)(xp + 8), d = *(const float4*)(xp + 12);
        xh0[0]=(half_t)a.x; xh0[1]=(half_t)a.y; xh0[2]=(half_t)a.z; xh0[3]=(half_t)a.w;
        xh0[4]=(half_t)b.x; xh0[5]=(half_t)b.y; xh0[6]=(half_t)b.z; xh0[7]=(half_t)b.w;
        xh1[0]=(half_t)c.x; xh1[1]=(half_t)c.y; xh1[2]=(half_t)c.z; xh1[3]=(half_t)c.w;
        xh1[4]=(half_t)d.x; xh1[5]=(half_t)d.y; xh1[6]=(half_t)d.z; xh1[7]=(half_t)d.w;
    }

    if (t < 64) { cO[t] = 0; cI[t] = 0; }
    if (t >= 64 && t < 192) pool[t - 64] = 0.f;
    for (int i = t; i < 4096; i += 256) Af[i] = 0.f;
    lds_barrier();                                           // B1

    atomicAdd(&Af[d0e * 64 + (s0e ^ ((d0e & 7) << 2))], w0e);
    atomicAdd(&cO[s0e], 1); atomicAdd(&cI[d0e], 1);
    if (e1v) {
        atomicAdd(&Af[d1e * 64 + (s1e ^ ((d1e & 7) << 2))], w1e);
        atomicAdd(&cO[s1e], 1); atomicAdd(&cI[d1e], 1);
    }
    lds_barrier();                                           // B2

    f16x8 afr[2];
    {
        const int r = w * 16 + lr;
        const int sw = (r & 7) << 2;
        const float rsi_l = rsqrtf((float)max(cI[r], 1));
        #pragma unroll
        for (int ks = 0; ks < 2; ks++) {
            const int c0 = ks * 32 + lk * 8;
            f32x4 v0 = *(const f32x4*)&Af[r * 64 + (c0 ^ sw)];
            f32x4 v1 = *(const f32x4*)&Af[r * 64 + ((c0 + 4) ^ sw)];
            f16x8 fr;
            #pragma unroll
            for (int j = 0; j < 4; j++)
                fr[j] = (half_t)(v0[j] * rsi_l * rsqrtf((float)max(cO[c0 + j], 1)));
            #pragma unroll
            for (int j = 0; j < 4; j++)
                fr[4 + j] = (half_t)(v1[j] * rsi_l * rsqrtf((float)max(cO[c0 + 4 + j], 1)));
            afr[ks] = fr;
        }
    }
    lds_barrier();                                           // B3

    #pragma unroll
    for (int i = 0; i < 8; i++) lds_st1h(R2, qc * 16 + i, srow, 128, xh0[i]);
    #pragma unroll
    for (int i = 0; i < 8; i++) lds_st1h(R2, qc * 16 + 8 + i, srow, 128, xh1[i]);
    lds_barrier();                                           // B4

    f32x4 hacc[8] = {};
    #pragma unroll
    for (int kf = 0; kf < 2; kf++) {
        f16x8 wb[8];
        #pragma unroll
        for (int nt = 0; nt < 8; nt++)
            wb[nt] = *(const f16x8*)&WT1[(nt * 16 + lr) * 64 + kf * 32 + lk * 8];
        #pragma unroll
        for (int j = 0; j < 2; j++) {
            const int ft = kf * 2 + j;
            f32x4 tacc = {};
            #pragma unroll
            for (int ks = 0; ks < 2; ks++) {
                f16x8 b = lds_ld8(R2, ft * 16 + lr, ks * 32 + lk * 8, 128);
                tacc = MFMA(afr[ks], b, tacc);
            }
            #pragma unroll
            for (int q = 0; q < 4; q++) scrS_st1(scrw, lk * 4 + q, j * 16 + lr, 64, tacc[q]);
        }
        f16x8 a1 = scrS_ld8(scrw, lr, lk * 8, 64);
        #pragma unroll
        for (int nt = 0; nt < 8; nt++) hacc[nt] = MFMA(a1, wb[nt], hacc[nt]);
    }
    lds_barrier();                                           // B5
    #pragma unroll
    for (int nt = 0; nt < 8; nt++) {
        int c = nt * 16 + lr;
        float bb = b1[c];
        #pragma unroll
        for (int q = 0; q < 4; q++)
            lds_st1(R2, c, w * 16 + lk * 4 + q, 128, fmaxf(hacc[nt][q] + bb, 0.f));
    }
    lds_barrier();                                           // B6

    f32x4 h2[8] = {};
    #pragma unroll
    for (int kf = 0; kf < 4; kf++) {
        f16x8 wb[8];
        #pragma unroll
        for (int nt = 0; nt < 8; nt++)
            wb[nt] = *(const f16x8*)&WT2[(nt * 16 + lr) * 128 + kf * 32 + lk * 8];
        #pragma unroll
        for (int j = 0; j < 2; j++) {
            const int ft = kf * 2 + j;
            f32x4 tacc = {};
            #pragma unroll
            for (int ks = 0; ks < 2; ks++) {
                f16x8 b = lds_ld8(R2, ft * 16 + lr, ks * 32 + lk * 8, 128);
                tacc = MFMA(afr[ks], b, tacc);
            }
            #pragma unroll
            for (int q = 0; q < 4; q++) scrS_st1(scrw, lk * 4 + q, j * 16 + lr, 64, tacc[q]);
        }
        f16x8 a1 = scrS_ld8(scrw, lr, lk * 8, 64);
        #pragma unroll
        for (int nt = 0; nt < 8; nt++) h2[nt] = MFMA(a1, wb[nt], h2[nt]);
    }
    #pragma unroll
    for (int nt = 0; nt < 8; nt++) {
        int c = nt * 16 + lr;
        float bb = b2[c];
        float ps = 0.f;
        #pragma unroll
        for (int q = 0; q < 4; q++) {
            int m = w * 16 + lk * 4 + q;
            float v = fmaxf(h2[nt][q] + bb, 0.f);
            ps += (m < NPI) ? v : 0.f;
        }
        ps += __shfl_xor(ps, 16);
        ps += __shfl_xor(ps, 32);
        if (lk == 0) atomicAdd(&pool[c], ps);
    }
    lds_barrier();                                           // B7
    {
        const int og = g / NPO, n = g - og * NPO;
        half_t* mT = mergedT + (size_t)og * 192 * 128 + n;
        if (t < 64) mT[(size_t)t * 128] = (half_t)ofv;
        else if (t < 192) mT[(size_t)t * 128] = (half_t)(pool[t - 64] * (1.f / NPI));
    }
}

// ---------------------------------------------------------------------------
// k_outer_one: the ENTIRE outer path in one 128-block kernel with manual
// grid syncs (device-scope atomics + threadfence; all blocks co-resident).
// Prologue: W3-6 convert (all blocks, grid-stride) + adjacency (blocks 0..15,
// global Af scratch). Then 4 conv layers (block = graph x 16-row slice,
// 4 feature-parallel waves) + pool + classifier (blocks 0..15).
// ---------------------------------------------------------------------------
__device__ __forceinline__ void gsync(int* ctr, int idx) {
    __syncthreads();
    if (threadIdx.x == 0) {
        __threadfence();
        atomicAdd(&ctr[idx], 1);
        while (atomicAdd(&ctr[idx], 0) < OB) __builtin_amdgcn_s_sleep(2);
        __threadfence();
    }
    __syncthreads();
}

template <int FIN>
__device__ __forceinline__ void do_layer(
    const f16x8* af, const half_t* __restrict__ ig,
    const half_t* __restrict__ WT, const float* __restrict__ bias,
    half_t* __restrict__ outg, int r0, half_t* scrT, half_t* hts,
    int w, int lr, int lk, int t)
{
    // T-step: wave w covers FIN/4 feature cols (TP 16-col tiles)
    constexpr int TP = FIN / 64;
    #pragma unroll
    for (int tt = 0; tt < TP; tt++) {
        const int ft = w * TP + tt;
        f32x4 tacc = {};
        #pragma unroll
        for (int ks = 0; ks < 4; ks++) {
            f16x8 b = *(const f16x8*)&ig[(size_t)(ft * 16 + lr) * 128 + ks * 32 + lk * 8];
            tacc = MFMA(af[ks], b, tacc);
        }
        #pragma unroll
        for (int q = 0; q < 4; q++)
            scrS_st1(scrT, lk * 4 + q, ft * 16 + lr, FIN * 2, tacc[q]);
    }
    __syncthreads();
    // H-step: wave w covers H-cols [w*32, w*32+32), K = FIN
    f32x4 hacc[2] = {};
    #pragma unroll
    for (int ks2 = 0; ks2 < FIN / 32; ks2++) {
        f16x8 a1 = scrS_ld8(scrT, lr, ks2 * 32 + lk * 8, FIN * 2);
        #pragma unroll
        for (int nt2 = 0; nt2 < 2; nt2++) {
            f16x8 wb = *(const f16x8*)&WT[(size_t)(w * 32 + nt2 * 16 + lr) * FIN
                                          + ks2 * 32 + lk * 8];
            hacc[nt2] = MFMA(a1, wb, hacc[nt2]);
        }
    }
    #pragma unroll
    for (int nt2 = 0; nt2 < 2; nt2++) {
        int c = w * 32 + nt2 * 16 + lr;
        float bb = bias[c];
        #pragma unroll
        for (int q = 0; q < 4; q++)
            hts[c * 16 + lk * 4 + q] = (half_t)fmaxf(hacc[nt2][q] + bb, 0.f);
    }
    __syncthreads();
    // coalesced feat-major writeback: outg[f][r0..r0+16)
    {
        int f = t >> 1, i0 = (t & 1) * 8;
        f16x8 v = *(const f16x8*)&hts[f * 16 + i0];
        *(f16x8*)&outg[(size_t)f * 128 + r0 + i0] = v;
    }
    __syncthreads();   // hts/scrT reuse safety (cross-layer handled by gsync)
}

__global__ __launch_bounds__(256) void k_outer_one(
    const float* __restrict__ W3, const float* __restrict__ W4,
    const float* __restrict__ W5, const float* __restrict__ W6,
    half_t* __restrict__ WT3, half_t* __restrict__ WT4,
    half_t* __restrict__ WT5, half_t* __restrict__ WT6,
    const float* __restrict__ ewo, const int* __restrict__ esrc,
    const int* __restrict__ edst,
    float* __restrict__ AfG, int* __restrict__ cOG, int* __restrict__ cIG,
    half_t* __restrict__ Aout, const half_t* __restrict__ mergedT,
    const float* __restrict__ b3, const float* __restrict__ b4,
    const float* __restrict__ b5, const float* __restrict__ b6,
    half_t* __restrict__ hT1, half_t* __restrict__ hT2,
    half_t* __restrict__ hT3, half_t* __restrict__ hT4,
    const float* __restrict__ Wc, const float* __restrict__ bc,
    int* __restrict__ ctr, float* __restrict__ out)
{
    __shared__ alignas(16) half_t scrT[16 * 192];   // 6KB
    __shared__ alignas(16) half_t hts[128 * 16];    // 4KB
    __shared__ float cls[NC];
    const int bid = blockIdx.x, t = threadIdx.x;
    const int w = t >> 6, l = t & 63, lr = l & 15, lk = l >> 4;

    // ---- prologue: W3..W6 -> WT (grid-stride over 73728 elems) ----
    for (int i = bid * 256 + t; i < 73728; i += OB * 256) {
        const float* src; half_t* dst; int K, ii;
        if (i < 24576) { src = W3; dst = WT3; K = 192; ii = i; }
        else {
            int r = i - 24576, m = r >> 14;
            ii = r & 16383; K = 128;
            src = (m == 0) ? W4 : (m == 1) ? W5 : W6;
            dst = (m == 0) ? WT4 : (m == 1) ? WT5 : WT6;
        }
        int c = ii & 127, k = ii >> 7;
        dst[c * K + k] = (half_t)src[k * 128 + c];
    }
    // ---- prologue: adjacency (blocks 0..15, global scratch pre-zeroed) ----
    if (bid < NB) {
        const int g = bid, nb = g * NPO, eb = g * EPO;
        float* Afg = AfG + (size_t)g * (NPO * NPO);
        int* cO = cOG + g * NPO; int* cI = cIG + g * NPO;
        for (int e = t; e < EPO; e += 256) {
            int s = esrc[eb + e] - nb, d = edst[eb + e] - nb;
            atomicAdd(&Afg[d * NPO + s], ewo[eb + e]);
            atomicAdd(&cO[s], 1); atomicAdd(&cI[d], 1);
        }
        __threadfence();
        __syncthreads();
        for (int i = t; i < 128 * 16; i += 256) {
            int d = i >> 4, s0 = (i & 15) * 8;
            float rsi_l = (d < NPO) ? rsqrtf((float)max(cI[d], 1)) : 0.f;
            f16x8 v;
            #pragma unroll
            for (int j = 0; j < 8; j++) {
                int s = s0 + j;
                float x = (d < NPO && s < NPO)
                    ? Afg[d * NPO + s] * rsi_l * rsqrtf((float)max(cO[s], 1)) : 0.f;
                v[j] = (half_t)x;
            }
            *(f16x8*)&Aout[(size_t)g * 16384 + d * 128 + s0] = v;
        }
    }
    gsync(ctr, 0);

    // ---- 4 conv layers ----
    const int og = bid >> 3, r0 = (bid & 7) * 16;
    f16x8 af[4];
    #pragma unroll
    for (int ks = 0; ks < 4; ks++)
        af[ks] = *(const f16x8*)&Aout[(size_t)og * 16384 + (size_t)(r0 + lr) * 128
                                      + ks * 32 + lk * 8];

    do_layer<192>(af, mergedT + (size_t)og * 192 * 128, WT3, b3,
                  hT1 + (size_t)og * 16384, r0, scrT, hts, w, lr, lk, t);
    gsync(ctr, 1);
    do_layer<128>(af, hT1 + (size_t)og * 16384, WT4, b4,
                  hT2 + (size_t)og * 16384, r0, scrT, hts, w, lr, lk, t);
    gsync(ctr, 2);
    do_layer<128>(af, hT2 + (size_t)og * 16384, WT5, b5,
                  hT3 + (size_t)og * 16384, r0, scrT, hts, w, lr, lk, t);
    gsync(ctr, 3);
    do_layer<128>(af, hT3 + (size_t)og * 16384, WT6, b6,
                  hT4 + (size_t)og * 16384, r0, scrT, hts, w, lr, lk, t);
    gsync(ctr, 4);

    // ---- pool + classifier (blocks 0..15) ----
    if (bid < NB) {
        if (t < NC) cls[t] = 0.f;
        __syncthreads();
        if (t < 128) {
            const half_t* hp = hT4 + (size_t)bid * 16384 + (size_t)t * 128;
            float s = 0.f;
            #pragma unroll
            for (int i = 0; i < 15; i++) {
                f16x8 v = *(const f16x8*)&hp[i * 8];
                #pragma unroll
                for (int j = 0; j < 8; j++) s += (float)v[j];
            }
            #pragma unroll
            for (int i = 120; i < 125; i++) s += (float)hp[i];
            const float val = s * (1.f / NPO);
            float p[NC];
            #pragma unroll
            for (int c = 0; c < NC; c++) p[c] = val * Wc[t * NC + c];
            #pragma unroll
            for (int off = 32; off >= 1; off >>= 1)
                #pragma unroll
                for (int c = 0; c < NC; c++) p[c] += __shfl_xor(p[c], off);
            if ((t & 63) == 0)
                #pragma unroll
                for (int c = 0; c < NC; c++) atomicAdd(&cls[c], p[c]);
        }
        __syncthreads();
        if (t < NC) out[bid * NC + t] = cls[t] + bc[t];
    }
}

extern "C" void kernel_launch(void* const* d_in, const int* in_sizes, int n_in,
                              void* d_out, int out_size, void* d_ws, size_t ws_size,
                              hipStream_t stream)
{
    const float* X       = (const float*)d_in[0];
    const float* outfeat = (const float*)d_in[1];
    const float* iew     = (const float*)d_in[2];
    const float* oew     = (const float*)d_in[3];
    const float* W1 = (const float*)d_in[4];  const float* b1 = (const float*)d_in[5];
    const float* W2 = (const float*)d_in[6];  const float* b2 = (const float*)d_in[7];
    const float* W3 = (const float*)d_in[8];  const float* b3 = (const float*)d_in[9];
    const float* W4 = (const float*)d_in[10]; const float* b4 = (const float*)d_in[11];
    const float* W5 = (const float*)d_in[12]; const float* b5 = (const float*)d_in[13];
    const float* W6 = (const float*)d_in[14]; const float* b6 = (const float*)d_in[15];
    const float* Wc = (const float*)d_in[16]; const float* bc = (const float*)d_in[17];
    const int* isrc = (const int*)d_in[18];   const int* idst = (const int*)d_in[19];
    const int* osrc = (const int*)d_in[20];   const int* odst = (const int*)d_in[21];

    char* base = (char*)d_ws;
    half_t* WT1 = (half_t*)(base + 0);
    half_t* WT2 = (half_t*)(base + 16384);
    half_t* WT3 = (half_t*)(base + 49152);     // [128][192] 48KB
    half_t* WT4 = (half_t*)(base + 98304);
    half_t* WT5 = (half_t*)(base + 131072);
    half_t* WT6 = (half_t*)(base + 163840);
    half_t* AoutG   = (half_t*)(base + 196608);   // [16][128][128]
    half_t* mergedT = (half_t*)(base + 720896);   // [16][192][128]
    half_t* hT1 = (half_t*)(base + 1507328);
    half_t* hT2 = (half_t*)(base + 2031616);
    half_t* hT3 = (half_t*)(base + 2555904);
    half_t* hT4 = (half_t*)(base + 3080192);      // ends 3604480
    int*    ctr = (int*)(base + 3604480);         // 8 ints (zeroed)
    float*  AfG = (float*)(base + 3604608);       // 16*15625*4 = 1000000B
    int*    cOG = (int*)(base + 4604608);         // 8000B
    int*    cIG = (int*)(base + 4612608);         // 8000B -> ends 4620608
    int*    zbase = (int*)(base + 3604480);
    const int zcount = (4620608 - 3604480) / 4;   // 254032 ints

    k_preW12<<<96, 256, 0, stream>>>(W1, W2, WT1, WT2, zbase, zcount);
    k_inner<<<N_OUT, 256, 0, stream>>>(X, outfeat, iew, isrc, idst,
                                       WT1, b1, WT2, b2, mergedT);
    k_outer_one<<<OB, 256, 0, stream>>>(W3, W4, W5, W6, WT3, WT4, WT5, WT6,
                                        oew, osrc, odst, AfG, cOG, cIG,
                                        AoutG, mergedT, b3, b4, b5, b6,
                                        hT1, hT2, hT3, hT4, Wc, bc, ctr,
                                        (float*)d_out);
}

// Round 15
// 115.764 us; speedup vs baseline: 1.4456x; 1.4456x over previous
//
#include <hip/hip_runtime.h>

#define NPI 50      // nodes per inner graph
#define EPI 400     // edges per inner graph
#define NPO 125     // nodes per outer graph
#define EPO 1000    // edges per outer graph
#define N_IN 100000
#define N_OUT 2000
#define NB 16       // batch graphs
#define NC 10

typedef _Float16 half_t;
typedef _Float16 f16x8 __attribute__((ext_vector_type(8)));
typedef _Float16 f16x4 __attribute__((ext_vector_type(4)));
typedef float f32x4 __attribute__((ext_vector_type(4)));

#define MFMA(a, b, c) __builtin_amdgcn_mfma_f32_16x16x32_f16(a, b, c, 0, 0, 0)

// LDS-only barrier (r12-proven neutral vs __syncthreads, keeps prefetches live).
__device__ __forceinline__ void lds_barrier() {
    asm volatile("s_waitcnt lgkmcnt(0)" ::: "memory");
    __builtin_amdgcn_s_barrier();
}

// Swizzled LDS helpers. XOR of (row&7) into byte bits 4..6 keeps ds_read_b128
// conflict-free when 16 lanes read 16 consecutive rows.
__device__ __forceinline__ f16x8 lds_ld8(const half_t* base, int row, int k, int strideB) {
    return *(const f16x8*)((const char*)base + row * strideB + ((k * 2) ^ ((row & 7) << 4)));
}
__device__ __forceinline__ void lds_st1(half_t* base, int row, int col, int strideB, float v) {
    *(half_t*)((char*)base + row * strideB + ((col * 2) ^ ((row & 7) << 4))) = (half_t)v;
}
__device__ __forceinline__ void lds_st1h(half_t* base, int row, int col, int strideB, half_t v) {
    *(half_t*)((char*)base + row * strideB + ((col * 2) ^ ((row & 7) << 4))) = v;
}
// b64 store of 4 node-contiguous halfs (col0 multiple of 4): 8B span stays
// contiguous under the XOR-bits-4..6 swizzle.
__device__ __forceinline__ void lds_st4h(half_t* base, int row, int col0, int strideB, f16x4 v) {
    *(f16x4*)((char*)base + row * strideB + ((col0 * 2) ^ ((row & 7) << 4))) = v;
}
// per-wave scratch [16][32] f16, stride 64B, XOR (row&3)<<4
__device__ __forceinline__ f16x8 scr_ld8(const half_t* base, int row, int k) {
    return *(const f16x8*)((const char*)base + row * 64 + ((k * 2) ^ ((row & 3) << 4)));
}
__device__ __forceinline__ void scr_st1(half_t* base, int row, int col, float v) {
    *(half_t*)((char*)base + row * 64 + ((col * 2) ^ ((row & 3) << 4))) = (half_t)v;
}

// ---------------------------------------------------------------------------
// k_pre: blocks 0..383 convert W1..W6 -> transposed f16; blocks 384..399 build
// dense outer adjacency Â_outer [16][128][128] f16 (row-major). [r4-proven]
// ---------------------------------------------------------------------------
__global__ __launch_bounds__(256) void k_pre(
    const float* __restrict__ W1, const float* __restrict__ W2,
    const float* __restrict__ W3, const float* __restrict__ W4,
    const float* __restrict__ W5, const float* __restrict__ W6,
    half_t* __restrict__ WT1, half_t* __restrict__ WT2,
    half_t* __restrict__ WT3, half_t* __restrict__ WT4,
    half_t* __restrict__ WT5, half_t* __restrict__ WT6,
    const float* __restrict__ ew, const int* __restrict__ esrc,
    const int* __restrict__ edst, half_t* __restrict__ Aout)
{
    __shared__ float Af[NPO * NPO];
    __shared__ int cO[NPO], cI[NPO];
    __shared__ float rso[NPO], rsi[NPO];
    const int t = threadIdx.x;

    if (blockIdx.x < 384) {
        int i = blockIdx.x * 256 + t;
        const float* src; half_t* dst; int K;
        if      (i < 8192)  { src = W1; dst = WT1; K = 64; }
        else if (i < 24576) { src = W2; dst = WT2; K = 128; i -= 8192; }
        else if (i < 49152) { src = W3; dst = WT3; K = 192; i -= 24576; }
        else if (i < 65536) { src = W4; dst = WT4; K = 128; i -= 49152; }
        else if (i < 81920) { src = W5; dst = WT5; K = 128; i -= 65536; }
        else                { src = W6; dst = WT6; K = 128; i -= 81920; }
        int c = i & 127, k = i >> 7;
        dst[c * K + k] = (half_t)src[k * 128 + c];
        return;
    }

    const int g = blockIdx.x - 384;
    const int nb = g * NPO, eb = g * EPO;
    for (int i = t; i < NPO * NPO; i += 256) Af[i] = 0.f;
    if (t < NPO) { cO[t] = 0; cI[t] = 0; }
    __syncthreads();
    for (int e = t; e < EPO; e += 256) {
        int s = esrc[eb + e] - nb, d = edst[eb + e] - nb;
        atomicAdd(&Af[d * NPO + s], ew[eb + e]);
        atomicAdd(&cO[s], 1); atomicAdd(&cI[d], 1);
    }
    __syncthreads();
    if (t < NPO) {
        rso[t] = rsqrtf((float)max(cO[t], 1));
        rsi[t] = rsqrtf((float)max(cI[t], 1));
    }
    __syncthreads();
    for (int i = t; i < 128 * 16; i += 256) {
        int d = i >> 4, s0 = (i & 15) * 8;
        f16x8 v;
        #pragma unroll
        for (int j = 0; j < 8; j++) {
            int s = s0 + j;
            float x = (d < NPO && s < NPO) ? Af[d * NPO + s] * rsi[d] * rso[s] : 0.f;
            v[j] = (half_t)x;
        }
        *(f16x8*)&Aout[(size_t)g * 16384 + d * 128 + s0] = v;
    }
}

// ---------------------------------------------------------------------------
// Inner fused, 5-barrier variant: the XT LDS stage is GONE — T1's B-operand
// fragments come straight from global X (L2-resident, OOB-clamped; Â's zero
// columns kill pad garbage). Af zeroing is b128; h1T writeback is b64.
// ---------------------------------------------------------------------------
__global__ __launch_bounds__(256, 5) void k_inner(
    const float* __restrict__ X, const float* __restrict__ outfeat,
    const float* __restrict__ ew, const int* __restrict__ esrc,
    const int* __restrict__ edst,
    const half_t* __restrict__ WT1, const float* __restrict__ b1,
    const half_t* __restrict__ WT2, const float* __restrict__ b2,
    half_t* __restrict__ merged)
{
    __shared__ alignas(16) char smem[21504];
    half_t* R2  = (half_t*)smem;             // [128][64] f16 swz s128 (h1T)
    float*  Af  = (float*)smem;              // [64][64] f32, bank-swizzled (alias)
    half_t* scr = (half_t*)(smem + 16384);   // [4 waves][16][32] f16
    float*  pool= (float*)(smem + 20480);    // [128]
    int*    cO  = (int*)(smem + 20992);      // [64]
    int*    cI  = (int*)(smem + 21248);      // [64]

    const int g = blockIdx.x, t = threadIdx.x;
    const int w = t >> 6, l = t & 63, lr = l & 15, lk = l >> 4;
    const int nb = g * NPI, eb = g * EPI;
    half_t* scrw = scr + w * 512;

    // ---- all global prefetches issued at kernel entry ----
    float ofv = (t < 64) ? outfeat[(size_t)g * 64 + t] : 0.f;
    int s0e, d0e; float w0e;
    { int e = eb + t; s0e = esrc[e] - nb; d0e = edst[e] - nb; w0e = ew[e]; }
    int s1e = 0, d1e = 0; float w1e = 0.f;
    const bool e1v = (t + 256 < EPI);
    if (e1v) { int e = eb + t + 256; s1e = esrc[e] - nb; d1e = edst[e] - nb; w1e = ew[e]; }
    // T1 B-fragments direct from X: frag(ft,ks) = X[node=ks*32+lk*8+j][ft*16+lr],
    // shared by all 4 waves (4x redundant L2 reads, zero LDS).
    f16x8 bx[8];
    #pragma unroll
    for (int fi = 0; fi < 4; fi++) {
        #pragma unroll
        for (int ks = 0; ks < 2; ks++) {
            f16x8 v;
            #pragma unroll
            for (int jj = 0; jj < 8; jj++) {
                int n = ks * 32 + lk * 8 + jj;
                int ridx = nb + n; if (ridx > N_IN - 1) ridx = N_IN - 1;
                v[jj] = (half_t)X[(size_t)ridx * 64 + fi * 16 + lr];
            }
            bx[fi * 2 + ks] = v;
        }
    }

    if (t < 64) { cO[t] = 0; cI[t] = 0; }
    if (t >= 64 && t < 192) pool[t - 64] = 0.f;
    {
        const f32x4 z4 = {0.f, 0.f, 0.f, 0.f};
        #pragma unroll
        for (int i = 0; i < 4; i++) *(f32x4*)&Af[(i * 256 + t) * 4] = z4;
    }
    lds_barrier();                                           // B1

    // edge scatter into bank-swizzled Af: element (d,s) at d*64 + (s^((d&7)<<2))
    atomicAdd(&Af[d0e * 64 + (s0e ^ ((d0e & 7) << 2))], w0e);
    atomicAdd(&cO[s0e], 1); atomicAdd(&cI[d0e], 1);
    if (e1v) {
        atomicAdd(&Af[d1e * 64 + (s1e ^ ((d1e & 7) << 2))], w1e);
        atomicAdd(&cO[s1e], 1); atomicAdd(&cI[d1e], 1);
    }
    lds_barrier();                                           // B2

    // ---- build Â A-fragments in registers: row = w*16+lr, ks in {0,1} ----
    f16x8 afr[2];
    {
        const int r = w * 16 + lr;
        const int sw = (r & 7) << 2;
        const float rsi_l = rsqrtf((float)max(cI[r], 1));
        #pragma unroll
        for (int ks = 0; ks < 2; ks++) {
            const int c0 = ks * 32 + lk * 8;
            f32x4 v0 = *(const f32x4*)&Af[r * 64 + (c0 ^ sw)];
            f32x4 v1 = *(const f32x4*)&Af[r * 64 + ((c0 + 4) ^ sw)];
            f16x8 fr;
            #pragma unroll
            for (int j = 0; j < 4; j++)
                fr[j] = (half_t)(v0[j] * rsi_l * rsqrtf((float)max(cO[c0 + j], 1)));
            #pragma unroll
            for (int j = 0; j < 4; j++)
                fr[4 + j] = (half_t)(v1[j] * rsi_l * rsqrtf((float)max(cO[c0 + 4 + j], 1)));
            afr[ks] = fr;
        }
    }
    lds_barrier();                                           // B3 (Af reads done)

    // ---- T1 = Â@X (strip-fused, B from registers) -> H1 = relu(T1@W1+b1) ----
    f32x4 hacc[8] = {};
    #pragma unroll
    for (int kf = 0; kf < 2; kf++) {
        f16x8 wb[8];
        #pragma unroll
        for (int nt = 0; nt < 8; nt++)
            wb[nt] = *(const f16x8*)&WT1[(nt * 16 + lr) * 64 + kf * 32 + lk * 8];
        #pragma unroll
        for (int j = 0; j < 2; j++) {
            const int ft = kf * 2 + j;
            f32x4 tacc = {};
            #pragma unroll
            for (int ks = 0; ks < 2; ks++)
                tacc = MFMA(afr[ks], bx[ft * 2 + ks], tacc);
            #pragma unroll
            for (int q = 0; q < 4; q++) scr_st1(scrw, lk * 4 + q, j * 16 + lr, tacc[q]);
        }
        f16x8 a1 = scr_ld8(scrw, lr, lk * 8);
        #pragma unroll
        for (int nt = 0; nt < 8; nt++) hacc[nt] = MFMA(a1, wb[nt], hacc[nt]);
    }
    // h1T writeback: b64 (4 node-contiguous halfs per store)
    #pragma unroll
    for (int nt = 0; nt < 8; nt++) {
        int c = nt * 16 + lr;
        float bb = b1[c];
        f16x4 hv;
        #pragma unroll
        for (int q = 0; q < 4; q++) hv[q] = (half_t)fmaxf(hacc[nt][q] + bb, 0.f);
        lds_st4h(R2, c, w * 16 + lk * 4, 128, hv);
    }
    lds_barrier();                                           // B4 (h1T visible)

    // ---- T2 = Â@h1 (strip-fused) -> H2 = relu(T2@W2+b2) -> masked pool ----
    f32x4 h2[8] = {};
    #pragma unroll
    for (int kf = 0; kf < 4; kf++) {
        f16x8 wb[8];
        #pragma unroll
        for (int nt = 0; nt < 8; nt++)
            wb[nt] = *(const f16x8*)&WT2[(nt * 16 + lr) * 128 + kf * 32 + lk * 8];
        #pragma unroll
        for (int j = 0; j < 2; j++) {
            const int ft = kf * 2 + j;
            f32x4 tacc = {};
            #pragma unroll
            for (int ks = 0; ks < 2; ks++) {
                f16x8 b = lds_ld8(R2, ft * 16 + lr, ks * 32 + lk * 8, 128);
                tacc = MFMA(afr[ks], b, tacc);
            }
            #pragma unroll
            for (int q = 0; q < 4; q++) scr_st1(scrw, lk * 4 + q, j * 16 + lr, tacc[q]);
        }
        f16x8 a1 = scr_ld8(scrw, lr, lk * 8);
        #pragma unroll
        for (int nt = 0; nt < 8; nt++) h2[nt] = MFMA(a1, wb[nt], h2[nt]);
    }
    #pragma unroll
    for (int nt = 0; nt < 8; nt++) {
        int c = nt * 16 + lr;
        float bb = b2[c];
        float ps = 0.f;
        #pragma unroll
        for (int q = 0; q < 4; q++) {
            int m = w * 16 + lk * 4 + q;
            float v = fmaxf(h2[nt][q] + bb, 0.f);
            ps += (m < NPI) ? v : 0.f;
        }
        ps += __shfl_xor(ps, 16);
        ps += __shfl_xor(ps, 32);
        if (lk == 0) atomicAdd(&pool[c], ps);
    }
    lds_barrier();                                           // B5
    if (t < 64) merged[(size_t)g * 192 + t] = (half_t)ofv;
    else if (t < 192) merged[(size_t)g * 192 + t] = (half_t)(pool[t - 64] * (1.f / NPI));
}

// ---------------------------------------------------------------------------
// Outer fused @1024 threads [r9/r10-proven]: Â in registers, WT register-
// prefetch, early stage loads, parallel classifier.
// ---------------------------------------------------------------------------
template <int FIN, bool STAGE, bool LAST>
__device__ __forceinline__ void outer_layer(
    const f16x8* afr, const half_t* __restrict__ mg,
    const half_t* __restrict__ WT, const float* __restrict__ bias,
    half_t* bufP, half_t* bufQ, float* pool,
    int wr, int wc, int lr, int lk, int t)
{
    f32x4 hacc[4] = {};
    constexpr int NCH = FIN / 64;
    f16x8 hv[NCH];
    if constexpr (STAGE) {
        const int s = t >> 3, fo = (t & 7) * 8;
        #pragma unroll
        for (int ch = 0; ch < NCH; ch++) {
            f16x8 z = {};
            hv[ch] = (s < NPO) ? *(const f16x8*)&mg[(size_t)s * 192 + ch * 64 + fo] : z;
        }
    }
    #pragma unroll
    for (int ch = 0; ch < NCH; ch++) {
        f16x8 wtb[8];
        #pragma unroll
        for (int ks2 = 0; ks2 < 2; ks2++)
            #pragma unroll
            for (int nt = 0; nt < 4; nt++)
                wtb[ks2 * 4 + nt] = *(const f16x8*)&WT[
                    (size_t)(wc * 64 + nt * 16 + lr) * FIN + ch * 64 + ks2 * 32 + lk * 8];
        if constexpr (STAGE) {
            const int s = t >> 3, fo = (t & 7) * 8;
            #pragma unroll
            for (int j = 0; j < 8; j++) lds_st1h(bufP, fo + j, s, 256, hv[ch][j]);
            lds_barrier();
        }
        const int rb = STAGE ? 0 : ch * 64;
        f32x4 tacc[2] = {};
        #pragma unroll
        for (int ks = 0; ks < 4; ks++) {
            #pragma unroll
            for (int nt = 0; nt < 2; nt++) {
                f16x8 b = lds_ld8(bufP, rb + wc * 32 + nt * 16 + lr, ks * 32 + lk * 8, 256);
                tacc[nt] = MFMA(afr[ks], b, tacc[nt]);
            }
        }
        #pragma unroll
        for (int nt = 0; nt < 2; nt++)
            #pragma unroll
            for (int q = 0; q < 4; q++)
                lds_st1(bufQ, wr * 16 + lk * 4 + q, wc * 32 + nt * 16 + lr, 128,
                        tacc[nt][q]);
        lds_barrier();
        #pragma unroll
        for (int ks2 = 0; ks2 < 2; ks2++) {
            f16x8 a1 = lds_ld8(bufQ, wr * 16 + lr, ks2 * 32 + lk * 8, 128);
            #pragma unroll
            for (int nt = 0; nt < 4; nt++)
                hacc[nt] = MFMA(a1, wtb[ks2 * 4 + nt], hacc[nt]);
        }
        lds_barrier();
    }
    if constexpr (!LAST) {
        #pragma unroll
        for (int nt = 0; nt < 4; nt++) {
            int c = wc * 64 + nt * 16 + lr;
            float bb = bias[c];
            #pragma unroll
            for (int q = 0; q < 4; q++)
                lds_st1(bufP, c, wr * 16 + lk * 4 + q, 256, fmaxf(hacc[nt][q] + bb, 0.f));
        }
        lds_barrier();
    } else {
        #pragma unroll
        for (int nt = 0; nt < 4; nt++) {
            int c = wc * 64 + nt * 16 + lr;
            float bb = bias[c];
            float ps = 0.f;
            #pragma unroll
            for (int q = 0; q < 4; q++) {
                int d = wr * 16 + lk * 4 + q;
                float v = fmaxf(hacc[nt][q] + bb, 0.f);
                ps += (d < NPO) ? v : 0.f;
            }
            ps += __shfl_xor(ps, 16);
            ps += __shfl_xor(ps, 32);
            if (lk == 0) atomicAdd(&pool[c], ps);
        }
        lds_barrier();
    }
}

__global__ __launch_bounds__(1024) void k_outer(
    const half_t* __restrict__ Aout, const half_t* __restrict__ merged,
    const half_t* __restrict__ WT3, const float* __restrict__ b3,
    const half_t* __restrict__ WT4, const float* __restrict__ b4,
    const half_t* __restrict__ WT5, const float* __restrict__ b5,
    const half_t* __restrict__ WT6, const float* __restrict__ b6,
    const float* __restrict__ Wc, const float* __restrict__ bc,
    float* __restrict__ out)
{
    __shared__ alignas(16) char smem[49704];
    half_t* bufP = (half_t*)smem;             // [128][256B] swz (h^T)
    half_t* bufQ = (half_t*)(smem + 32768);   // [128][128B] swz (T chunk)
    float*  pool = (float*)(smem + 49152);    // [128]
    float*  cls  = (float*)(smem + 49664);    // [10]

    const int g = blockIdx.x, t = threadIdx.x;
    const int w = t >> 6, l = t & 63, lr = l & 15, lk = l >> 4;
    const int wr = w & 7, wc = w >> 3;
    const half_t* mg = merged + (size_t)g * NPO * 192;

    f16x8 afr[4];
    #pragma unroll
    for (int ks = 0; ks < 4; ks++)
        afr[ks] = *(const f16x8*)&Aout[(size_t)g * 16384
                                       + (wr * 16 + lr) * 128 + ks * 32 + lk * 8];
    if (t < 128) pool[t] = 0.f;
    if (t >= 128 && t < 128 + NC) cls[t - 128] = 0.f;
    lds_barrier();

    outer_layer<192, true,  false>(afr, mg, WT3, b3, bufP, bufQ, pool, wr, wc, lr, lk, t);
    outer_layer<128, false, false>(afr, nullptr, WT4, b4, bufP, bufQ, pool, wr, wc, lr, lk, t);
    outer_layer<128, false, false>(afr, nullptr, WT5, b5, bufP, bufQ, pool, wr, wc, lr, lk, t);
    outer_layer<128, false, true >(afr, nullptr, WT6, b6, bufP, bufQ, pool, wr, wc, lr, lk, t);

    if (t < 128) {
        float val = pool[t] * (1.f / NPO);
        float p[NC];
        #pragma unroll
        for (int c = 0; c < NC; c++) p[c] = val * Wc[t * NC + c];
        #pragma unroll
        for (int off = 32; off >= 1; off >>= 1)
            #pragma unroll
            for (int c = 0; c < NC; c++) p[c] += __shfl_xor(p[c], off);
        if ((t & 63) == 0)
            #pragma unroll
            for (int c = 0; c < NC; c++) atomicAdd(&cls[c], p[c]);
    }
    lds_barrier();
    if (t < NC) out[g * NC + t] = cls[t] + bc[t];
}

extern "C" void kernel_launch(void* const* d_in, const int* in_sizes, int n_in,
                              void* d_out, int out_size, void* d_ws, size_t ws_size,
                              hipStream_t stream)
{
    const float* X       = (const float*)d_in[0];
    const float* outfeat = (const float*)d_in[1];
    const float* iew     = (const float*)d_in[2];
    const float* oew     = (const float*)d_in[3];
    const float* W1 = (const float*)d_in[4];  const float* b1 = (const float*)d_in[5];
    const float* W2 = (const float*)d_in[6];  const float* b2 = (const float*)d_in[7];
    const float* W3 = (const float*)d_in[8];  const float* b3 = (const float*)d_in[9];
    const float* W4 = (const float*)d_in[10]; const float* b4 = (const float*)d_in[11];
    const float* W5 = (const float*)d_in[12]; const float* b5 = (const float*)d_in[13];
    const float* W6 = (const float*)d_in[14]; const float* b6 = (const float*)d_in[15];
    const float* Wc = (const float*)d_in[16]; const float* bc = (const float*)d_in[17];
    const int* isrc = (const int*)d_in[18];   const int* idst = (const int*)d_in[19];
    const int* osrc = (const int*)d_in[20];   const int* odst = (const int*)d_in[21];

    char* base = (char*)d_ws;
    half_t* WT1 = (half_t*)(base + 0);        // [128][64]
    half_t* WT2 = (half_t*)(base + 16384);    // [128][128]
    half_t* WT3 = (half_t*)(base + 49152);    // [128][192]
    half_t* WT4 = (half_t*)(base + 98304);    // [128][128]
    half_t* WT5 = (half_t*)(base + 131072);   // [128][128]
    half_t* WT6 = (half_t*)(base + 163840);   // [128][128]
    half_t* AoutG  = (half_t*)(base + 196608);   // [16][128][128]
    half_t* merged = (half_t*)(base + 720896);   // [2000][192]

    k_pre<<<400, 256, 0, stream>>>(W1, W2, W3, W4, W5, W6,
                                   WT1, WT2, WT3, WT4, WT5, WT6,
                                   oew, osrc, odst, AoutG);
    k_inner<<<N_OUT, 256, 0, stream>>>(X, outfeat, iew, isrc, idst,
                                       WT1, b1, WT2, b2, merged);
    k_outer<<<NB, 1024, 0, stream>>>(AoutG, merged, WT3, b3, WT4, b4,
                                     WT5, b5, WT6, b6, Wc, bc, (float*)d_out);
}